// Round 15
// baseline (298.176 us; speedup 1.0000x reference)
//
#include <hip/hip_runtime.h>

namespace {
constexpr int E_N  = 131072;
constexpr int FEA  = 256;
constexpr int RAD  = 64;
constexpr int HID  = 128;
constexpr int WN   = 256;
constexpr int EPB  = 64;    // edges per block
constexpr int NT   = 256;   // 4 waves
constexpr int LSTR = 68;    // len tile stride (floats), 16B-aligned
constexpr int FRAG_HI_SHORTS = 2 * 4 * 16 * 64 * 8;  // 65536: W2 hi, both pipes
constexpr int W1HI = 2 * FRAG_HI_SHORTS;             // 131072: W1 hi base
constexpr int W1LO_DELTA = 2 * 2 * 8 * 64 * 8;       // 16384 shorts
}

typedef short short8v __attribute__((ext_vector_type(8)));   // 8 bf16 (4 VGPRs)
typedef float floatx4 __attribute__((ext_vector_type(4)));   // MFMA accumulator

__device__ __forceinline__ unsigned bf16rne(float x) {       // f32 -> bf16 (RNE)
    const unsigned u = __float_as_uint(x);
    return (u + 0x7FFFu + ((u >> 16) & 1u)) >> 16;
}
__device__ __forceinline__ float bf16tof(unsigned h) {
    return __uint_as_float(h << 16);
}
__device__ __forceinline__ void bf16split(float x, unsigned& hi, unsigned& lo) {
    hi = bf16rne(x);
    lo = bf16rne(x - bf16tof(hi));
}

// Intra-wave LDS fence: all prior LDS ops retired; compiler may not reorder
// memory accesses across it (r3 lesson + guide rule #18).
#define LDS_FENCE() do { \
    asm volatile("s_waitcnt lgkmcnt(0)" ::: "memory"); \
    __builtin_amdgcn_sched_barrier(0); \
} while (0)

union FragU { uint4 u; short8v v; };

// ---- Prep: split W2 into bf16 hi/lo MFMA B-fragments in d_ws ----
__global__ __launch_bounds__(64)
void prep_w2(const float* __restrict__ W2a, const float* __restrict__ W2b,
             unsigned short* __restrict__ frag)
{
    const int lane = threadIdx.x;
    const int nb = blockIdx.x, kt = blockIdx.y, pipe = blockIdx.z;
    const float* __restrict__ W2 = pipe ? W2b : W2a;
    const int g = lane >> 4, s = lane & 15;
    unsigned ph[4], pl[4];
    #pragma unroll
    for (int p = 0; p < 4; ++p) {
        const float x0 = W2[(size_t)(32*kt + 8*g + 2*p)     * WN + nb*16 + s];
        const float x1 = W2[(size_t)(32*kt + 8*g + 2*p + 1) * WN + nb*16 + s];
        unsigned h0, l0, h1, l1;
        bf16split(x0, h0, l0);
        bf16split(x1, h1, l1);
        ph[p] = h0 | (h1 << 16);
        pl[p] = l0 | (l1 << 16);
    }
    const size_t fi = (size_t)pipe * 32768 + (size_t)((kt*16 + nb)*64 + lane) * 8;
    *(uint4*)(frag + fi)                  = make_uint4(ph[0], ph[1], ph[2], ph[3]);
    *(uint4*)(frag + FRAG_HI_SHORTS + fi) = make_uint4(pl[0], pl[1], pl[2], pl[3]);
}

// ---- Prep: split W1 into bf16 hi/lo MFMA B-fragments (same convention) ----
__global__ __launch_bounds__(64)
void prep_w1(const float* __restrict__ W1a, const float* __restrict__ W1b,
             unsigned short* __restrict__ frag)
{
    const int lane = threadIdx.x;
    const int nb = blockIdx.x, kt = blockIdx.y, pipe = blockIdx.z;
    const float* __restrict__ W1 = pipe ? W1b : W1a;
    const int g = lane >> 4, s = lane & 15;
    unsigned ph[4], pl[4];
    #pragma unroll
    for (int p = 0; p < 4; ++p) {
        const float x0 = W1[(size_t)(32*kt + 8*g + 2*p)     * HID + nb*16 + s];
        const float x1 = W1[(size_t)(32*kt + 8*g + 2*p + 1) * HID + nb*16 + s];
        unsigned h0, l0, h1, l1;
        bf16split(x0, h0, l0);
        bf16split(x1, h1, l1);
        ph[p] = h0 | (h1 << 16);
        pl[p] = l0 | (l1 << 16);
    }
    const size_t fi = (size_t)W1HI + (size_t)pipe * 8192
                    + (size_t)((kt*8 + nb)*64 + lane) * 8;
    *(uint4*)(frag + fi)              = make_uint4(ph[0], ph[1], ph[2], ph[3]);
    *(uint4*)(frag + W1LO_DELTA + fi) = make_uint4(pl[0], pl[1], pl[2], pl[3]);
}

__global__ __launch_bounds__(NT, 5)
void fused_mlp_dtp(
    const float* __restrict__ fea_a, const float* __restrict__ vec_a,
    const float* __restrict__ len_a, const float* __restrict__ b1_a,
    const float* __restrict__ g_a,   const float* __restrict__ be_a,
    const float* __restrict__ fea_b, const float* __restrict__ vec_b,
    const float* __restrict__ len_b, const float* __restrict__ b1_b,
    const float* __restrict__ g_b,   const float* __restrict__ be_b,
    const unsigned short* __restrict__ fragW,
    float* __restrict__ out)
{
    // 32768 B LDS, time-aliased:
    //   phases 1-2: len f32[64][68] in [0, 17408)
    //   phases 3-4: actH bf16[64][128] in [0,16K), actL in [16K,32K)
    //               (16B-granule XOR swizzle: granule ^= row&7)
    //   epilogue:   wave w stage (3136 B) at [w*4096, w*4096+3136) -- inside
    //               wave w's OWN actH rows -> no cross-wave hazard
    __shared__ __align__(16) char smemraw[32768];
    float*          lenT = (float*)smemraw;
    unsigned short* actH = (unsigned short*)smemraw;
    unsigned short* actL = (unsigned short*)(smemraw + 16384);

    const int pipe = blockIdx.y;
    const float* __restrict__ fea = pipe ? fea_b : fea_a;
    const float* __restrict__ vec = pipe ? vec_b : vec_a;
    const float* __restrict__ len = pipe ? len_b : len_a;
    const float* __restrict__ b1  = pipe ? b1_b  : b1_a;
    const float* __restrict__ g   = pipe ? g_b   : g_a;
    const float* __restrict__ be  = pipe ? be_b  : be_a;
    float* __restrict__ outp = out + (size_t)pipe * (size_t)E_N * FEA;

    const int t    = threadIdx.x;
    const int lane = t & 63;
    const int wv_  = t >> 6;
    const int s_   = lane & 15, g_ = lane >> 4;
    const long e0  = (long)blockIdx.x * EPB;

    // ---------- Phase 1: stage len tile [64][68] (cross-wave) ----------
    {
        const float4* __restrict__ src = (const float4*)(len + e0 * RAD);
        #pragma unroll
        for (int i = 0; i < (EPB * RAD / 4) / NT; ++i) {
            const int f = t + i * NT;            // 0..1023
            const float4 v = src[f];
            const int e = f >> 4, kq = (f & 15) * 4;
            *(float4*)(&lenT[e * LSTR + kq]) = v;
        }
    }
    __syncthreads();

    // ---------- Phase 2: h = len @ W1 via split-bf16 MFMA ----------
    floatx4 acc2[8];
    #pragma unroll
    for (int nb = 0; nb < 8; ++nb) {
        acc2[nb][0] = 0.f; acc2[nb][1] = 0.f; acc2[nb][2] = 0.f; acc2[nb][3] = 0.f;
    }
    {
        const int eA = wv_ * 16 + s_;
        const unsigned short* __restrict__ fH1 = fragW + W1HI + (size_t)pipe * 8192;
        const unsigned short* __restrict__ fL1 = fH1 + W1LO_DELTA;
        #pragma unroll
        for (int kt = 0; kt < 2; ++kt) {
            float xs[8];
            {
                const float4 x0 = *(const float4*)(&lenT[eA*LSTR + 32*kt + 8*g_]);
                const float4 x1 = *(const float4*)(&lenT[eA*LSTR + 32*kt + 8*g_ + 4]);
                xs[0]=x0.x; xs[1]=x0.y; xs[2]=x0.z; xs[3]=x0.w;
                xs[4]=x1.x; xs[5]=x1.y; xs[6]=x1.z; xs[7]=x1.w;
            }
            FragU ahu, alu;
            {
                unsigned ph[4], pl[4];
                #pragma unroll
                for (int p = 0; p < 4; ++p) {
                    unsigned h0, l0, h1, l1;
                    bf16split(xs[2*p],     h0, l0);
                    bf16split(xs[2*p + 1], h1, l1);
                    ph[p] = h0 | (h1 << 16);
                    pl[p] = l0 | (l1 << 16);
                }
                ahu.u = make_uint4(ph[0], ph[1], ph[2], ph[3]);
                alu.u = make_uint4(pl[0], pl[1], pl[2], pl[3]);
            }
            const short8v ah = ahu.v, al = alu.v;
            const size_t kb = (size_t)(kt * 8) * 512 + (size_t)lane * 8;
            #pragma unroll
            for (int nb = 0; nb < 8; ++nb) {
                const short8v bh = *(const short8v*)(fH1 + kb + nb * 512);
                const short8v bl = *(const short8v*)(fL1 + kb + nb * 512);
                acc2[nb] = __builtin_amdgcn_mfma_f32_16x16x32_bf16(ah, bh, acc2[nb], 0, 0, 0);
                acc2[nb] = __builtin_amdgcn_mfma_f32_16x16x32_bf16(ah, bl, acc2[nb], 0, 0, 0);
                acc2[nb] = __builtin_amdgcn_mfma_f32_16x16x32_bf16(al, bh, acc2[nb], 0, 0, 0);
            }
        }
    }
    __syncthreads();   // all len reads done; act region may now be written

    // ---------- Phase 3: b1 + LayerNorm + SiLU in registers, split-store ----
    // C-layout: acc2[nb][r] = h[edge 16w+4g_+r][col 16nb+s_].
    {
        float hv[8][4];
        float sum[4] = {0.f, 0.f, 0.f, 0.f};
        float sq [4] = {0.f, 0.f, 0.f, 0.f};
        #pragma unroll
        for (int nb = 0; nb < 8; ++nb) {
            const float b1v = b1[16*nb + s_];
            #pragma unroll
            for (int r = 0; r < 4; ++r) {
                const float v = acc2[nb][r] + b1v;
                hv[nb][r] = v;
                sum[r] += v;
                sq [r] += v * v;
            }
        }
        float mu[4], iv[4];
        #pragma unroll
        for (int r = 0; r < 4; ++r) {
            float s1 = sum[r], s2 = sq[r];
            s1 += __shfl_xor(s1, 1); s1 += __shfl_xor(s1, 2);
            s1 += __shfl_xor(s1, 4); s1 += __shfl_xor(s1, 8);
            s2 += __shfl_xor(s2, 1); s2 += __shfl_xor(s2, 2);
            s2 += __shfl_xor(s2, 4); s2 += __shfl_xor(s2, 8);
            mu[r] = s1 * (1.0f / HID);
            float var = s2 * (1.0f / HID) - mu[r] * mu[r];
            var = fmaxf(var, 0.0f);
            iv[r] = rsqrtf(var + 1e-5f);
        }
        const int rowb = wv_ * 16 + 4 * g_;
        #pragma unroll
        for (int nb = 0; nb < 8; ++nb) {
            const float gv  = g [16*nb + s_];
            const float bev = be[16*nb + s_];
            const int blkbase = 2*nb + (s_ >> 3);     // granule of col 16nb+s_
            #pragma unroll
            for (int r = 0; r < 4; ++r) {
                const float hn = (hv[nb][r] - mu[r]) * iv[r] * gv + bev;
                const float sl = hn / (1.0f + __expf(-hn));
                unsigned h, l;
                bf16split(sl, h, l);
                const int e = rowb + r;
                const int idx = e * 128 + ((blkbase ^ (e & 7)) << 3) + (s_ & 7);
                actH[idx] = (unsigned short)h;
                actL[idx] = (unsigned short)l;
            }
        }
    }
    LDS_FENCE();   // wave-local: this wave's act rows are complete

    // ---------- Phase 4: w = silu @ W2 via split-bf16 MFMA ----------
    floatx4 acc[16];
    #pragma unroll
    for (int nb = 0; nb < 16; ++nb) {
        acc[nb][0] = 0.f; acc[nb][1] = 0.f; acc[nb][2] = 0.f; acc[nb][3] = 0.f;
    }
    {
        const int eA = wv_ * 16 + s_;
        const unsigned short* __restrict__ fH = fragW + (size_t)pipe * 32768;
        const unsigned short* __restrict__ fL = fH + FRAG_HI_SHORTS;
        for (int kt = 0; kt < 4; ++kt) {
            const int sg = (4*kt + g_) ^ (s_ & 7);     // swizzled granule
            FragU ahu, alu;
            ahu.u = *(const uint4*)(actH + eA * 128 + sg * 8);
            alu.u = *(const uint4*)(actL + eA * 128 + sg * 8);
            const short8v ah = ahu.v, al = alu.v;
            const size_t kb = (size_t)(kt * 16) * 512 + (size_t)lane * 8;
            #pragma unroll
            for (int nb = 0; nb < 16; ++nb) {
                const short8v bh = *(const short8v*)(fH + kb + nb * 512);
                const short8v bl = *(const short8v*)(fL + kb + nb * 512);
                acc[nb] = __builtin_amdgcn_mfma_f32_16x16x32_bf16(ah, bh, acc[nb], 0, 0, 0);
                acc[nb] = __builtin_amdgcn_mfma_f32_16x16x32_bf16(ah, bl, acc[nb], 0, 0, 0);
                acc[nb] = __builtin_amdgcn_mfma_f32_16x16x32_bf16(al, bh, acc[nb], 0, 0, 0);
            }
        }
    }
    LDS_FENCE();   // this wave's act reads retired; stage region reusable

    // ---------- Epilogue: DTP from C-layout; wave-local stage, no barriers --
    {
        const float c2 = 0.70710678118654752f;   // 1/sqrt(2)
        const float c3 = 0.40824829046386302f;   // 1/sqrt(6)
        float* sStage = (float*)(smemraw + wv_ * 4096);   // wave's own act rows
        for (int r = 0; r < 4; ++r) {
            const long e = e0 + wv_ * 16 + 4 * g_ + r;
            const float4 y = *(const float4*)(vec + e * 4);
            const float* __restrict__ fr   = fea  + e * (size_t)FEA;
            float* __restrict__       orow = outp + e * (size_t)FEA;
            #pragma unroll
            for (int q = 0; q < 4; ++q) {
                const int u = 16 * q + s_;
                const float w1 = acc[q     ][r];
                const float w2 = acc[q + 4 ][r];
                const float w3 = acc[q + 8 ][r];
                const float w4 = acc[q + 12][r];
                const float x0  = fr[u];
                const float x1a = fr[64 + 3*u + 0];
                const float x1b = fr[64 + 3*u + 1];
                const float x1c = fr[64 + 3*u + 2];
                const float dot = x1a*y.y + x1b*y.z + x1c*y.w;
                orow[u] = w1*x0*y.x*c2 + w4*dot*c3;
                sStage[g_*196 + 3*u + 0] = (w2*x0*y.y + w3*x1a*y.x) * c2;
                sStage[g_*196 + 3*u + 1] = (w2*x0*y.z + w3*x1b*y.x) * c2;
                sStage[g_*196 + 3*u + 2] = (w2*x0*y.w + w3*x1c*y.x) * c2;
            }
            LDS_FENCE();   // stage visible to all lanes of this wave
            #pragma unroll
            for (int rr = 0; rr < 3; ++rr) {
                const int flat = rr * 256 + lane * 4;     // 0..764
                const int eloc = flat / 192;              // 0..3 (g-group)
                const int pos  = flat % 192;              // 16B aligned
                const float4 v = *(const float4*)(&sStage[eloc * 196 + pos]);
                *(float4*)(&outp[(e0 + wv_*16 + 4*eloc + r) * (size_t)FEA + 64 + pos]) = v;
            }
            LDS_FENCE();   // drain reads retired before next r overwrites
        }
    }
}

extern "C" void kernel_launch(void* const* d_in, const int* in_sizes, int n_in,
                              void* d_out, int out_size, void* d_ws, size_t ws_size,
                              hipStream_t stream) {
    (void)in_sizes; (void)n_in; (void)ws_size; (void)out_size;
    const float* fea_a = (const float*)d_in[0];
    const float* vec_a = (const float*)d_in[1];
    const float* len_a = (const float*)d_in[2];
    const float* W1_a  = (const float*)d_in[3];
    const float* b1_a  = (const float*)d_in[4];
    const float* g_a   = (const float*)d_in[5];
    const float* be_a  = (const float*)d_in[6];
    const float* W2_a  = (const float*)d_in[7];
    const float* fea_b = (const float*)d_in[8];
    const float* vec_b = (const float*)d_in[9];
    const float* len_b = (const float*)d_in[10];
    const float* W1_b  = (const float*)d_in[11];
    const float* b1_b  = (const float*)d_in[12];
    const float* g_b   = (const float*)d_in[13];
    const float* be_b  = (const float*)d_in[14];
    const float* W2_b  = (const float*)d_in[15];
    float* out = (float*)d_out;
    unsigned short* frag = (unsigned short*)d_ws;   // needs 320 KB

    hipLaunchKernelGGL(prep_w2, dim3(16, 4, 2), dim3(64), 0, stream,
                       W2_a, W2_b, frag);
    hipLaunchKernelGGL(prep_w1, dim3(8, 2, 2), dim3(64), 0, stream,
                       W1_a, W1_b, frag);

    dim3 grid(E_N / EPB, 2);
    dim3 block(NT);
    hipLaunchKernelGGL(fused_mlp_dtp, grid, block, 0, stream,
                       fea_a, vec_a, len_a, b1_a, g_a, be_a,
                       fea_b, vec_b, len_b, b1_b, g_b, be_b,
                       frag, out);
}

// Round 16
// 196.444 us; speedup vs baseline: 1.5179x; 1.5179x over previous
//
#include <hip/hip_runtime.h>

namespace {
constexpr int E_N  = 131072;
constexpr int FEA  = 256;
constexpr int RAD  = 64;
constexpr int HID  = 128;
constexpr int WN   = 256;
constexpr int EPB  = 64;    // edges per block
constexpr int NT   = 256;   // 4 waves
constexpr int LSTR = 68;    // len tile stride (floats), 16B-aligned
constexpr int FRAG_HI_SHORTS = 2 * 4 * 16 * 64 * 8;  // 65536: W2 hi, both pipes
constexpr int W1HI = 2 * FRAG_HI_SHORTS;             // 131072: W1 hi base
constexpr int W1LO_DELTA = 2 * 2 * 8 * 64 * 8;       // 16384 shorts
}

typedef short short8v __attribute__((ext_vector_type(8)));   // 8 bf16 (4 VGPRs)
typedef float floatx4 __attribute__((ext_vector_type(4)));   // MFMA accumulator

__device__ __forceinline__ unsigned bf16rne(float x) {       // f32 -> bf16 (RNE)
    const unsigned u = __float_as_uint(x);
    return (u + 0x7FFFu + ((u >> 16) & 1u)) >> 16;
}
__device__ __forceinline__ float bf16tof(unsigned h) {
    return __uint_as_float(h << 16);
}
__device__ __forceinline__ void bf16split(float x, unsigned& hi, unsigned& lo) {
    hi = bf16rne(x);
    lo = bf16rne(x - bf16tof(hi));
}

// Intra-wave LDS fence: all prior LDS ops retired; compiler may not reorder
// memory accesses across it (r3 lesson + guide rule #18).
#define LDS_FENCE() do { \
    asm volatile("s_waitcnt lgkmcnt(0)" ::: "memory"); \
    __builtin_amdgcn_sched_barrier(0); \
} while (0)

union FragU { uint4 u; short8v v; };

// ---- Prep: split W2 into bf16 hi/lo MFMA B-fragments in d_ws ----
__global__ __launch_bounds__(64)
void prep_w2(const float* __restrict__ W2a, const float* __restrict__ W2b,
             unsigned short* __restrict__ frag)
{
    const int lane = threadIdx.x;
    const int nb = blockIdx.x, kt = blockIdx.y, pipe = blockIdx.z;
    const float* __restrict__ W2 = pipe ? W2b : W2a;
    const int g = lane >> 4, s = lane & 15;
    unsigned ph[4], pl[4];
    #pragma unroll
    for (int p = 0; p < 4; ++p) {
        const float x0 = W2[(size_t)(32*kt + 8*g + 2*p)     * WN + nb*16 + s];
        const float x1 = W2[(size_t)(32*kt + 8*g + 2*p + 1) * WN + nb*16 + s];
        unsigned h0, l0, h1, l1;
        bf16split(x0, h0, l0);
        bf16split(x1, h1, l1);
        ph[p] = h0 | (h1 << 16);
        pl[p] = l0 | (l1 << 16);
    }
    const size_t fi = (size_t)pipe * 32768 + (size_t)((kt*16 + nb)*64 + lane) * 8;
    *(uint4*)(frag + fi)                  = make_uint4(ph[0], ph[1], ph[2], ph[3]);
    *(uint4*)(frag + FRAG_HI_SHORTS + fi) = make_uint4(pl[0], pl[1], pl[2], pl[3]);
}

// ---- Prep: split W1 into bf16 hi/lo MFMA B-fragments (same convention) ----
__global__ __launch_bounds__(64)
void prep_w1(const float* __restrict__ W1a, const float* __restrict__ W1b,
             unsigned short* __restrict__ frag)
{
    const int lane = threadIdx.x;
    const int nb = blockIdx.x, kt = blockIdx.y, pipe = blockIdx.z;
    const float* __restrict__ W1 = pipe ? W1b : W1a;
    const int g = lane >> 4, s = lane & 15;
    unsigned ph[4], pl[4];
    #pragma unroll
    for (int p = 0; p < 4; ++p) {
        const float x0 = W1[(size_t)(32*kt + 8*g + 2*p)     * HID + nb*16 + s];
        const float x1 = W1[(size_t)(32*kt + 8*g + 2*p + 1) * HID + nb*16 + s];
        unsigned h0, l0, h1, l1;
        bf16split(x0, h0, l0);
        bf16split(x1, h1, l1);
        ph[p] = h0 | (h1 << 16);
        pl[p] = l0 | (l1 << 16);
    }
    const size_t fi = (size_t)W1HI + (size_t)pipe * 8192
                    + (size_t)((kt*8 + nb)*64 + lane) * 8;
    *(uint4*)(frag + fi)              = make_uint4(ph[0], ph[1], ph[2], ph[3]);
    *(uint4*)(frag + W1LO_DELTA + fi) = make_uint4(pl[0], pl[1], pl[2], pl[3]);
}

__global__ __launch_bounds__(NT, 4)
void fused_mlp_dtp(
    const float* __restrict__ fea_a, const float* __restrict__ vec_a,
    const float* __restrict__ len_a, const float* __restrict__ b1_a,
    const float* __restrict__ g_a,   const float* __restrict__ be_a,
    const float* __restrict__ fea_b, const float* __restrict__ vec_b,
    const float* __restrict__ len_b, const float* __restrict__ b1_b,
    const float* __restrict__ g_b,   const float* __restrict__ be_b,
    const unsigned short* __restrict__ fragW,
    float* __restrict__ out)
{
    // 32768 B LDS, time-aliased:
    //   phases 1-2: len f32[64][68] in [0, 17408)
    //   phases 3-4: actH bf16[64][128] in [0,16K), actL in [16K,32K)
    //               (16B-granule XOR swizzle: granule ^= row&7)
    //   epilogue:   wave w stage (3136 B) at [w*4096, w*4096+3136) -- inside
    //               wave w's OWN actH rows -> no cross-wave hazard
    __shared__ __align__(16) char smemraw[32768];
    float*          lenT = (float*)smemraw;
    unsigned short* actH = (unsigned short*)smemraw;
    unsigned short* actL = (unsigned short*)(smemraw + 16384);

    const int pipe = blockIdx.y;
    const float* __restrict__ fea = pipe ? fea_b : fea_a;
    const float* __restrict__ vec = pipe ? vec_b : vec_a;
    const float* __restrict__ len = pipe ? len_b : len_a;
    const float* __restrict__ b1  = pipe ? b1_b  : b1_a;
    const float* __restrict__ g   = pipe ? g_b   : g_a;
    const float* __restrict__ be  = pipe ? be_b  : be_a;
    float* __restrict__ outp = out + (size_t)pipe * (size_t)E_N * FEA;

    const int t    = threadIdx.x;
    const int lane = t & 63;
    const int wv_  = t >> 6;
    const int s_   = lane & 15, g_ = lane >> 4;
    const long e0  = (long)blockIdx.x * EPB;

    // ---------- Phase 1: stage len tile [64][68] (cross-wave) ----------
    {
        const float4* __restrict__ src = (const float4*)(len + e0 * RAD);
        #pragma unroll
        for (int i = 0; i < (EPB * RAD / 4) / NT; ++i) {
            const int f = t + i * NT;            // 0..1023
            const float4 v = src[f];
            const int e = f >> 4, kq = (f & 15) * 4;
            *(float4*)(&lenT[e * LSTR + kq]) = v;
        }
    }
    __syncthreads();

    // ---------- Phase 2: h = len @ W1 via split-bf16 MFMA ----------
    floatx4 acc2[8];
    #pragma unroll
    for (int nb = 0; nb < 8; ++nb) {
        acc2[nb][0] = 0.f; acc2[nb][1] = 0.f; acc2[nb][2] = 0.f; acc2[nb][3] = 0.f;
    }
    {
        const int eA = wv_ * 16 + s_;
        const unsigned short* __restrict__ fH1 = fragW + W1HI + (size_t)pipe * 8192;
        const unsigned short* __restrict__ fL1 = fH1 + W1LO_DELTA;
        #pragma unroll
        for (int kt = 0; kt < 2; ++kt) {
            float xs[8];
            {
                const float4 x0 = *(const float4*)(&lenT[eA*LSTR + 32*kt + 8*g_]);
                const float4 x1 = *(const float4*)(&lenT[eA*LSTR + 32*kt + 8*g_ + 4]);
                xs[0]=x0.x; xs[1]=x0.y; xs[2]=x0.z; xs[3]=x0.w;
                xs[4]=x1.x; xs[5]=x1.y; xs[6]=x1.z; xs[7]=x1.w;
            }
            FragU ahu, alu;
            {
                unsigned ph[4], pl[4];
                #pragma unroll
                for (int p = 0; p < 4; ++p) {
                    unsigned h0, l0, h1, l1;
                    bf16split(xs[2*p],     h0, l0);
                    bf16split(xs[2*p + 1], h1, l1);
                    ph[p] = h0 | (h1 << 16);
                    pl[p] = l0 | (l1 << 16);
                }
                ahu.u = make_uint4(ph[0], ph[1], ph[2], ph[3]);
                alu.u = make_uint4(pl[0], pl[1], pl[2], pl[3]);
            }
            const short8v ah = ahu.v, al = alu.v;
            const size_t kb = (size_t)(kt * 8) * 512 + (size_t)lane * 8;
            #pragma unroll
            for (int nb = 0; nb < 8; ++nb) {
                const short8v bh = *(const short8v*)(fH1 + kb + nb * 512);
                const short8v bl = *(const short8v*)(fL1 + kb + nb * 512);
                acc2[nb] = __builtin_amdgcn_mfma_f32_16x16x32_bf16(ah, bh, acc2[nb], 0, 0, 0);
                acc2[nb] = __builtin_amdgcn_mfma_f32_16x16x32_bf16(ah, bl, acc2[nb], 0, 0, 0);
                acc2[nb] = __builtin_amdgcn_mfma_f32_16x16x32_bf16(al, bh, acc2[nb], 0, 0, 0);
            }
        }
    }
    __syncthreads();   // all len reads done; act region may now be written

    // ---------- Phase 3: b1 + LayerNorm + SiLU in registers, split-store ----
    // C-layout: acc2[nb][r] = h[edge 16w+4g_+r][col 16nb+s_].
    {
        float hv[8][4];
        float sum[4] = {0.f, 0.f, 0.f, 0.f};
        float sq [4] = {0.f, 0.f, 0.f, 0.f};
        #pragma unroll
        for (int nb = 0; nb < 8; ++nb) {
            const float b1v = b1[16*nb + s_];
            #pragma unroll
            for (int r = 0; r < 4; ++r) {
                const float v = acc2[nb][r] + b1v;
                hv[nb][r] = v;
                sum[r] += v;
                sq [r] += v * v;
            }
        }
        float mu[4], iv[4];
        #pragma unroll
        for (int r = 0; r < 4; ++r) {
            float s1 = sum[r], s2 = sq[r];
            s1 += __shfl_xor(s1, 1); s1 += __shfl_xor(s1, 2);
            s1 += __shfl_xor(s1, 4); s1 += __shfl_xor(s1, 8);
            s2 += __shfl_xor(s2, 1); s2 += __shfl_xor(s2, 2);
            s2 += __shfl_xor(s2, 4); s2 += __shfl_xor(s2, 8);
            mu[r] = s1 * (1.0f / HID);
            float var = s2 * (1.0f / HID) - mu[r] * mu[r];
            var = fmaxf(var, 0.0f);
            iv[r] = rsqrtf(var + 1e-5f);
        }
        const int rowb = wv_ * 16 + 4 * g_;
        #pragma unroll
        for (int nb = 0; nb < 8; ++nb) {
            const float gv  = g [16*nb + s_];
            const float bev = be[16*nb + s_];
            const int blkbase = 2*nb + (s_ >> 3);     // granule of col 16nb+s_
            #pragma unroll
            for (int r = 0; r < 4; ++r) {
                const float hn = (hv[nb][r] - mu[r]) * iv[r] * gv + bev;
                const float sl = hn / (1.0f + __expf(-hn));
                unsigned h, l;
                bf16split(sl, h, l);
                const int e = rowb + r;
                const int idx = e * 128 + ((blkbase ^ (e & 7)) << 3) + (s_ & 7);
                actH[idx] = (unsigned short)h;
                actL[idx] = (unsigned short)l;
            }
        }
    }
    LDS_FENCE();   // wave-local: this wave's act rows are complete

    // ---------- Phase 4: w = silu @ W2 via split-bf16 MFMA ----------
    floatx4 acc[16];
    #pragma unroll
    for (int nb = 0; nb < 16; ++nb) {
        acc[nb][0] = 0.f; acc[nb][1] = 0.f; acc[nb][2] = 0.f; acc[nb][3] = 0.f;
    }
    {
        const int eA = wv_ * 16 + s_;
        const unsigned short* __restrict__ fH = fragW + (size_t)pipe * 32768;
        const unsigned short* __restrict__ fL = fH + FRAG_HI_SHORTS;
        for (int kt = 0; kt < 4; ++kt) {
            const int sg = (4*kt + g_) ^ (s_ & 7);     // swizzled granule
            FragU ahu, alu;
            ahu.u = *(const uint4*)(actH + eA * 128 + sg * 8);
            alu.u = *(const uint4*)(actL + eA * 128 + sg * 8);
            const short8v ah = ahu.v, al = alu.v;
            const size_t kb = (size_t)(kt * 16) * 512 + (size_t)lane * 8;
            #pragma unroll
            for (int nb = 0; nb < 16; ++nb) {
                const short8v bh = *(const short8v*)(fH + kb + nb * 512);
                const short8v bl = *(const short8v*)(fL + kb + nb * 512);
                acc[nb] = __builtin_amdgcn_mfma_f32_16x16x32_bf16(ah, bh, acc[nb], 0, 0, 0);
                acc[nb] = __builtin_amdgcn_mfma_f32_16x16x32_bf16(ah, bl, acc[nb], 0, 0, 0);
                acc[nb] = __builtin_amdgcn_mfma_f32_16x16x32_bf16(al, bh, acc[nb], 0, 0, 0);
            }
        }
    }
    LDS_FENCE();   // this wave's act reads retired; stage region reusable

    // ---------- Epilogue: DTP from C-layout; wave-local stage, no barriers --
    {
        const float c2 = 0.70710678118654752f;   // 1/sqrt(2)
        const float c3 = 0.40824829046386302f;   // 1/sqrt(6)
        float* sStage = (float*)(smemraw + wv_ * 4096);   // wave's own act rows
        for (int r = 0; r < 4; ++r) {
            const long e = e0 + wv_ * 16 + 4 * g_ + r;
            const float4 y = *(const float4*)(vec + e * 4);
            const float* __restrict__ fr   = fea  + e * (size_t)FEA;
            float* __restrict__       orow = outp + e * (size_t)FEA;
            #pragma unroll
            for (int q = 0; q < 4; ++q) {
                const int u = 16 * q + s_;
                const float w1 = acc[q     ][r];
                const float w2 = acc[q + 4 ][r];
                const float w3 = acc[q + 8 ][r];
                const float w4 = acc[q + 12][r];
                const float x0  = fr[u];
                const float x1a = fr[64 + 3*u + 0];
                const float x1b = fr[64 + 3*u + 1];
                const float x1c = fr[64 + 3*u + 2];
                const float dot = x1a*y.y + x1b*y.z + x1c*y.w;
                orow[u] = w1*x0*y.x*c2 + w4*dot*c3;
                sStage[g_*196 + 3*u + 0] = (w2*x0*y.y + w3*x1a*y.x) * c2;
                sStage[g_*196 + 3*u + 1] = (w2*x0*y.z + w3*x1b*y.x) * c2;
                sStage[g_*196 + 3*u + 2] = (w2*x0*y.w + w3*x1c*y.x) * c2;
            }
            LDS_FENCE();   // stage visible to all lanes of this wave
            #pragma unroll
            for (int rr = 0; rr < 3; ++rr) {
                const int flat = rr * 256 + lane * 4;     // 0..764
                const int eloc = flat / 192;              // 0..3 (g-group)
                const int pos  = flat % 192;              // 16B aligned
                const float4 v = *(const float4*)(&sStage[eloc * 196 + pos]);
                *(float4*)(&outp[(e0 + wv_*16 + 4*eloc + r) * (size_t)FEA + 64 + pos]) = v;
            }
            LDS_FENCE();   // drain reads retired before next r overwrites
        }
    }
}

extern "C" void kernel_launch(void* const* d_in, const int* in_sizes, int n_in,
                              void* d_out, int out_size, void* d_ws, size_t ws_size,
                              hipStream_t stream) {
    (void)in_sizes; (void)n_in; (void)ws_size; (void)out_size;
    const float* fea_a = (const float*)d_in[0];
    const float* vec_a = (const float*)d_in[1];
    const float* len_a = (const float*)d_in[2];
    const float* W1_a  = (const float*)d_in[3];
    const float* b1_a  = (const float*)d_in[4];
    const float* g_a   = (const float*)d_in[5];
    const float* be_a  = (const float*)d_in[6];
    const float* W2_a  = (const float*)d_in[7];
    const float* fea_b = (const float*)d_in[8];
    const float* vec_b = (const float*)d_in[9];
    const float* len_b = (const float*)d_in[10];
    const float* W1_b  = (const float*)d_in[11];
    const float* b1_b  = (const float*)d_in[12];
    const float* g_b   = (const float*)d_in[13];
    const float* be_b  = (const float*)d_in[14];
    const float* W2_b  = (const float*)d_in[15];
    float* out = (float*)d_out;
    unsigned short* frag = (unsigned short*)d_ws;   // needs 320 KB

    hipLaunchKernelGGL(prep_w2, dim3(16, 4, 2), dim3(64), 0, stream,
                       W2_a, W2_b, frag);
    hipLaunchKernelGGL(prep_w1, dim3(8, 2, 2), dim3(64), 0, stream,
                       W1_a, W1_b, frag);

    dim3 grid(E_N / EPB, 2);
    dim3 block(NT);
    hipLaunchKernelGGL(fused_mlp_dtp, grid, block, 0, stream,
                       fea_a, vec_a, len_a, b1_a, g_a, be_a,
                       fea_b, vec_b, len_b, b1_b, g_b, be_b,
                       frag, out);
}